// Round 1
// baseline (257.977 us; speedup 1.0000x reference)
//
#include <hip/hip_runtime.h>

// MN neuron forward sim: T=1000 sequential steps, 64x512 independent chains.
// One thread per (b,n) chain; double-buffered K=10 timestep prefetch for MLP.
// CORRECTNESS: binary spike output => must be bit-exact f32 vs numpy ref.
// => exact reference op order, no FMA contraction, selects for spike resets.

#define T_STEPS 1000
#define B_DIM 64
#define N_DIM 512
#define BN (B_DIM * N_DIM)   // 32768

// f32-rounded constants (decimals are exact f64 reprs of the f32 values)
#define C_DT   0.01f
#define C_EL   (-0.07f)
#define C_VR   (-0.07f)
#define C_TR   (-0.06f)
#define C_TINF (-0.05f)
#define C_B    12.77495288848877f
#define C_G    45.24007797241211f
#define C_K1   200.0f
#define C_K2   20.0f
#define C_R1   0.3858567178249359f
#define C_R2   (-1.1421641111373901f)

__device__ __forceinline__ float mn_step(float xt, float lin, float av,
                                         float A1v, float A2v,
                                         float& V, float& i1, float& i2,
                                         float& Thr)
{
#pragma clang fp contract(off)
    // i1 = i1 - K1*i1*DT   (order: (K1*i1)*DT, then subtract)
    i1 = i1 - (C_K1 * i1) * C_DT;
    // i2 = i2 - K2*i2*DT
    i2 = i2 - (C_K2 * i2) * C_DT;
    // V = V + DT*(linear*xt + i1 + i2 - G*(V-EL)) / C   (C==1.0 -> exact identity)
    float p  = lin * xt;
    float q  = p + i1;
    float r  = q + i2;
    float e  = V - C_EL;
    float g  = C_G * e;
    float s  = r - g;
    float d  = C_DT * s;
    V = V + d;
    // Thr = Thr + DT*(a*(V-EL) - B*(Thr-TINF))   (uses NEW V)
    float e2 = V - C_EL;
    float u  = av * e2;
    float w  = Thr - C_TINF;
    float bw = C_B * w;
    float s2 = u - bw;
    float d2 = C_DT * s2;
    Thr = Thr + d2;
    // spk = (V - Thr) > 0
    float diff = V - Thr;
    bool  sb   = diff > 0.0f;
    float spk  = sb ? 1.0f : 0.0f;
    // resets: blend-with-{0,1} is value-exact as select (only +/-0 sign diffs)
    float i1r = (C_R1 * i1) + A1v;
    float i2r = (C_R2 * i2) + A2v;
    i1  = sb ? i1r : i1;
    i2  = sb ? i2r : i2;
    float tm = fmaxf(Thr, C_TR);
    Thr = sb ? tm : Thr;
    V   = sb ? C_VR : V;
    return spk;
}

__global__ __launch_bounds__(64) void mn_neuron_kernel(
    const float* __restrict__ x, const float* __restrict__ linear,
    const float* __restrict__ a, const float* __restrict__ A1,
    const float* __restrict__ A2, float* __restrict__ out)
{
#pragma clang fp contract(off)
    const int idx = blockIdx.x * 64 + threadIdx.x;   // b*N + n
    const int n   = idx & (N_DIM - 1);

    const float lin = linear[n];
    const float av  = a[n];
    const float A1v = A1[n];
    const float A2v = A2[n];

    float V   = C_EL;
    float i1  = 0.0f;
    float i2  = 0.0f;
    float Thr = C_TINF;

    constexpr int K  = 10;              // prefetch chunk (timesteps)
    constexpr int NC = T_STEPS / K;     // 100 chunks (even)
    float bufA[K], bufB[K];

    const float* xp = x + idx;
    float*       op = out + idx;

    // prologue: chunk 0 -> bufA
#pragma unroll
    for (int j = 0; j < K; ++j) bufA[j] = xp[(size_t)j * BN];

    for (int c = 0; c < NC; c += 2) {
        // prefetch chunk c+1 -> bufB (c+1 <= NC-1 always since NC even)
        {
            const float* p = xp + (size_t)(c + 1) * K * BN;
#pragma unroll
            for (int j = 0; j < K; ++j) bufB[j] = p[(size_t)j * BN];
        }
        // compute chunk c from bufA
        {
            float* o = op + (size_t)c * K * BN;
#pragma unroll
            for (int j = 0; j < K; ++j) {
                float spk = mn_step(bufA[j], lin, av, A1v, A2v, V, i1, i2, Thr);
                o[(size_t)j * BN] = spk;
            }
        }
        // prefetch chunk c+2 -> bufA
        if (c + 2 < NC) {
            const float* p = xp + (size_t)(c + 2) * K * BN;
#pragma unroll
            for (int j = 0; j < K; ++j) bufA[j] = p[(size_t)j * BN];
        }
        // compute chunk c+1 from bufB
        {
            float* o = op + (size_t)(c + 1) * K * BN;
#pragma unroll
            for (int j = 0; j < K; ++j) {
                float spk = mn_step(bufB[j], lin, av, A1v, A2v, V, i1, i2, Thr);
                o[(size_t)j * BN] = spk;
            }
        }
    }
}

extern "C" void kernel_launch(void* const* d_in, const int* in_sizes, int n_in,
                              void* d_out, int out_size, void* d_ws, size_t ws_size,
                              hipStream_t stream) {
    const float* x      = (const float*)d_in[0];
    const float* linear = (const float*)d_in[1];
    const float* a      = (const float*)d_in[2];
    const float* A1     = (const float*)d_in[3];
    const float* A2     = (const float*)d_in[4];
    float* out = (float*)d_out;

    // 32768 chains, 64 threads/block -> 512 blocks (2 per CU over 256 CUs)
    mn_neuron_kernel<<<BN / 64, 64, 0, stream>>>(x, linear, a, A1, A2, out);
}

// Round 2
// 234.774 us; speedup vs baseline: 1.0988x; 1.0988x over previous
//
#include <hip/hip_runtime.h>

// MN neuron forward sim: T=1000 sequential steps, 64x512 independent chains.
// Round 2 structure: producer/consumer wave specialization per block.
//   wave 1 (producer): global -> LDS double-buffer via global_load_lds w=16
//   wave 0 (consumer): recurrence, x from LDS (ds_read imm offsets), stores out
// CORRECTNESS: binary spike output => bit-exact f32 vs numpy ref:
//   exact reference op order, no FMA contraction, selects for spike resets.

#define T_STEPS 1000
#define B_DIM 64
#define N_DIM 512
#define BN (B_DIM * N_DIM)   // 32768

#define K_CHUNK 20
#define NCHUNK (T_STEPS / K_CHUNK)   // 50

// f32-rounded constants
#define C_DT   0.01f
#define C_EL   (-0.07f)
#define C_VR   (-0.07f)
#define C_TR   (-0.06f)
#define C_TINF (-0.05f)
#define C_B    12.77495288848877f
#define C_G    45.24007797241211f
#define C_K1   200.0f
#define C_K2   20.0f
#define C_R1   0.3858567178249359f
#define C_R2   (-1.1421641111373901f)

typedef const __attribute__((address_space(1))) void* gp_t;
typedef __attribute__((address_space(3))) void* lp_t;

__device__ __forceinline__ float mn_step(float xt, float lin, float av,
                                         float A1v, float A2v,
                                         float& V, float& i1, float& i2,
                                         float& Thr)
{
#pragma clang fp contract(off)
    i1 = i1 - (C_K1 * i1) * C_DT;
    i2 = i2 - (C_K2 * i2) * C_DT;
    float p  = lin * xt;
    float q  = p + i1;
    float r  = q + i2;
    float e  = V - C_EL;
    float g  = C_G * e;
    float s  = r - g;
    float d  = C_DT * s;
    V = V + d;
    float e2 = V - C_EL;
    float u  = av * e2;
    float w  = Thr - C_TINF;
    float bw = C_B * w;
    float s2 = u - bw;
    float d2 = C_DT * s2;
    Thr = Thr + d2;
    float diff = V - Thr;
    bool  sb   = diff > 0.0f;
    float spk  = sb ? 1.0f : 0.0f;
    float i1r = (C_R1 * i1) + A1v;
    float i2r = (C_R2 * i2) + A2v;
    i1  = sb ? i1r : i1;
    i2  = sb ? i2r : i2;
    float tm = fmaxf(Thr, C_TR);
    Thr = sb ? tm : Thr;
    V   = sb ? C_VR : V;
    return spk;
}

__global__ __launch_bounds__(128) void mn_neuron_kernel(
    const float* __restrict__ x, const float* __restrict__ linear,
    const float* __restrict__ a, const float* __restrict__ A1,
    const float* __restrict__ A2, float* __restrict__ out)
{
#pragma clang fp contract(off)
    // lds[buf][t_in_chunk][lane]
    __shared__ float lds[2][K_CHUNK][64];

    const int lane = threadIdx.x & 63;
    const int wid  = threadIdx.x >> 6;     // 0 = consumer, 1 = producer
    const int blk  = blockIdx.x;

    if (wid == 1) {
        // ---- producer ----
        // width-16 global_load_lds: lane l loads 16B covering
        // row (l>>4) of the 4-row group, floats (l&15)*4 .. +3.
        // LDS dest = uniform base + l*16  ->  lds[buf][s*4 + (l>>4)][(l&15)*4..]
        const float* pl = x + (size_t)(lane >> 4) * BN
                            + (size_t)blk * 64 + (size_t)(lane & 15) * 4;

        // prologue: chunk 0 -> buf 0
        {
#pragma unroll
            for (int s = 0; s < K_CHUNK / 4; ++s) {
                __builtin_amdgcn_global_load_lds(
                    (gp_t)(pl + (size_t)(s * 4) * BN),
                    (lp_t)&lds[0][s * 4][0], 16, 0, 0);
            }
            __builtin_amdgcn_s_waitcnt(0x0F70);  // vmcnt(0) only
        }
        __syncthreads();

        for (int c = 0; c < NCHUNK; ++c) {
            if (c + 1 < NCHUNK) {
                const float* pc = pl + (size_t)((c + 1) * K_CHUNK) * BN;
                float* dst = &lds[(c + 1) & 1][0][0];
#pragma unroll
                for (int s = 0; s < K_CHUNK / 4; ++s) {
                    __builtin_amdgcn_global_load_lds(
                        (gp_t)(pc + (size_t)(s * 4) * BN),
                        (lp_t)(dst + s * 4 * 64), 16, 0, 0);
                }
                __builtin_amdgcn_s_waitcnt(0x0F70);  // vmcnt(0) only
            }
            __syncthreads();
        }
    } else {
        // ---- consumer ----
        const int idx = blk * 64 + lane;       // b*N + n
        const int n   = idx & (N_DIM - 1);

        const float lin = linear[n];
        const float av  = a[n];
        const float A1v = A1[n];
        const float A2v = A2[n];

        float V   = C_EL;
        float i1  = 0.0f;
        float i2  = 0.0f;
        float Thr = C_TINF;

        float* op = out + idx;

        __syncthreads();   // matches producer prologue barrier

        for (int c = 0; c < NCHUNK; ++c) {
            const float* src = &lds[c & 1][0][lane];
#pragma unroll
            for (int j = 0; j < K_CHUNK; ++j) {
                float xt  = src[j * 64];   // ds_read_b32, imm offset j*256
                float spk = mn_step(xt, lin, av, A1v, A2v, V, i1, i2, Thr);
                *op = spk;
                op += BN;
            }
            __syncthreads();
        }
    }
}

extern "C" void kernel_launch(void* const* d_in, const int* in_sizes, int n_in,
                              void* d_out, int out_size, void* d_ws, size_t ws_size,
                              hipStream_t stream) {
    const float* x      = (const float*)d_in[0];
    const float* linear = (const float*)d_in[1];
    const float* a      = (const float*)d_in[2];
    const float* A1     = (const float*)d_in[3];
    const float* A2     = (const float*)d_in[4];
    float* out = (float*)d_out;

    // 512 blocks x 128 threads (1 consumer wave + 1 producer wave each)
    mn_neuron_kernel<<<BN / 64, 128, 0, stream>>>(x, linear, a, A1, A2, out);
}